// Round 5
// baseline (556.547 us; speedup 1.0000x reference)
//
#include <hip/hip_runtime.h>
#include <stdint.h>

// Problem constants (fixed by setup_inputs): B=8, T=4096, D=H=512
#define NB 8
#define NT 4096
#define ND 512
#define NH 512
#define NN 1024        // 2H
#define NM (NB * NT)   // 32768 GEMM rows
#define NK 512         // GEMM K = D
#define NCH 128        // scan chunks along T
#define CTS 32         // steps per chunk (NCH*CTS == NT)

typedef __bf16 bf16x8 __attribute__((ext_vector_type(8)));
typedef float floatx4 __attribute__((ext_vector_type(4)));
typedef unsigned short ushortx8 __attribute__((ext_vector_type(8)));
typedef unsigned int uint_g __attribute__((address_space(1)));
typedef unsigned int uint_l __attribute__((address_space(3)));

__device__ __forceinline__ float bf2f(unsigned short u) {
    union { unsigned int i; float f; } v; v.i = ((unsigned int)u) << 16; return v.f;
}
__device__ __forceinline__ unsigned short f2bf(float f) {
    union { float f; unsigned int i; } v; v.f = f;
    return (unsigned short)((v.i + 0x7FFFu + ((v.i >> 16) & 1u)) >> 16);
}

// async 16B global->LDS; HW writes lane i at (wave-uniform base) + i*16
__device__ __forceinline__ void load_lds16(const void* g, void* l) {
    __builtin_amdgcn_global_load_lds((const uint_g*)g, (uint_l*)l, 16, 0, 0);
}

// gate math: h_t = a*h + z*g(hpre), a=sigmoid(-k), z=sigmoid(k)
__device__ __forceinline__ void gate_av(unsigned short ku, unsigned short pu,
                                        float& a, float& v) {
    float k = bf2f(ku), p = bf2f(pu);
    float e = __expf(k);
    a = __builtin_amdgcn_rcpf(1.0f + e);
    float z = e * a;  // sigmoid(k)
    float gneg = __builtin_amdgcn_rcpf(1.0f + __expf(-p));
    float g = (p >= 0.0f) ? (p + 0.5f) : gneg;
    v = z * g;
}

// ------- Kernel 1: prep = Wt transpose (blocks 0..511) + LayerNorm --------
// Wt rows are PERMUTED so gh columns come out channel-interleaved:
// original W col n (n<512: k-gate h=n; n>=512: h_pre h=n-512) -> Wt row
// perm(n) = 2*(n&511) + (n>>9).  gh[row][2h] = k_h, gh[row][2h+1] = p_h.
__global__ __launch_bounds__(256) void prep_kernel(const float* __restrict__ x,
                                                   const float* __restrict__ gamma,
                                                   const float* __restrict__ beta,
                                                   const float* __restrict__ W,
                                                   unsigned short* __restrict__ xn,
                                                   unsigned short* __restrict__ Wt) {
    if (blockIdx.x < 512) {
        // W (K x N) -> Wt (perm(N) x K) bf16, 32x32 tile
        __shared__ float tile[32][33];
        int bid = blockIdx.x;
        int n0 = (bid & 31) * 32;
        int k0 = (bid >> 5) * 32;
        int tx = threadIdx.x & 31, ty = threadIdx.x >> 5;  // 32 x 8
#pragma unroll
        for (int j = 0; j < 4; ++j)
            tile[ty + j * 8][tx] = W[(size_t)(k0 + ty + j * 8) * NN + n0 + tx];
        __syncthreads();
#pragma unroll
        for (int j = 0; j < 4; ++j) {
            int n = n0 + ty + j * 8;
            int np = 2 * (n & 511) + (n >> 9);
            Wt[(size_t)np * NK + k0 + tx] = f2bf(tile[tx][ty + j * 8]);
        }
        return;
    }
    // LayerNorm: one wave per row
    int wid = threadIdx.x >> 6, lane = threadIdx.x & 63;
    size_t row = (size_t)(blockIdx.x - 512) * 4 + wid;
    const float4* xr = (const float4*)(x + row * ND);
    float4 v0 = xr[lane];
    float4 v1 = xr[lane + 64];
    float s  = (v0.x + v0.y) + (v0.z + v0.w) + (v1.x + v1.y) + (v1.z + v1.w);
    float sq = v0.x * v0.x + v0.y * v0.y + v0.z * v0.z + v0.w * v0.w
             + v1.x * v1.x + v1.y * v1.y + v1.z * v1.z + v1.w * v1.w;
#pragma unroll
    for (int off = 32; off > 0; off >>= 1) {
        s  += __shfl_xor(s,  off, 64);
        sq += __shfl_xor(sq, off, 64);
    }
    float mu   = s * (1.0f / ND);
    float var  = sq * (1.0f / ND) - mu * mu;
    float rstd = rsqrtf(var + 1e-10f);
    const float4* gr = (const float4*)gamma;
    const float4* br = (const float4*)beta;
    float4 g0 = gr[lane], g1 = gr[lane + 64];
    float4 b0 = br[lane], b1 = br[lane + 64];
    ushort4 o0, o1;
    o0.x = f2bf((v0.x - mu) * rstd * g0.x + b0.x);
    o0.y = f2bf((v0.y - mu) * rstd * g0.y + b0.y);
    o0.z = f2bf((v0.z - mu) * rstd * g0.z + b0.z);
    o0.w = f2bf((v0.w - mu) * rstd * g0.w + b0.w);
    o1.x = f2bf((v1.x - mu) * rstd * g1.x + b1.x);
    o1.y = f2bf((v1.y - mu) * rstd * g1.y + b1.y);
    o1.z = f2bf((v1.z - mu) * rstd * g1.z + b1.z);
    o1.w = f2bf((v1.w - mu) * rstd * g1.w + b1.w);
    ushort4* xo = (ushort4*)(xn + row * ND);
    xo[lane]      = o0;
    xo[lane + 64] = o1;
}

// ---- Kernel 2: GEMM gh = xn @ W (bf16 MFMA) + fused chunk aggregates -----
// A: xn [NM x NK]; Bt: Wt [NN x NK] (rows permuted -> C cols interleaved).
// C: gh [NM x NN]. Tile 128x128, BK=64, 4 waves (2x2), wave = 64x64.
// Block order: mt fastest (nt-fast regressed: A-tile sharers on diff XCDs).
// Epilogue: store C, fence+barrier, then each thread re-reads its (chunk,h)
// pair-column from the L2-hot tile and writes scan chunk aggregates (A,V).
__global__ __launch_bounds__(256) void gemm_kernel(const unsigned short* __restrict__ A,
                                                   const unsigned short* __restrict__ Bt,
                                                   unsigned short* __restrict__ C,
                                                   float* __restrict__ cA,
                                                   float* __restrict__ cV) {
    __shared__ __align__(16) unsigned short As[128 * 64];
    __shared__ __align__(16) unsigned short Bs[128 * 64];
    int tid  = threadIdx.x;
    int lane = tid & 63;
    int wid  = tid >> 6;
    int wm = wid & 1, wn = wid >> 1;
    int bx = blockIdx.x;
    int mt = bx & 255;   // 256 M-tiles
    int nt = bx >> 8;    // 8 N-tiles
    const int Rm = mt * 128, Rn = nt * 128;

    // staging lane decomposition: 64 lanes = 8 rows x 8 chunks(16B)
    int rloc = lane >> 3;          // row within 8-row group
    int cl   = lane & 7;           // LDS chunk slot
    int cg   = cl ^ rloc;          // global chunk (XOR swizzle)

    int frow = lane & 15;          // MFMA m/n index
    int quad = lane >> 4;          // MFMA k-group
    int fx   = lane & 7;           // swizzle key for frag reads

    floatx4 acc[4][4];
#pragma unroll
    for (int i = 0; i < 4; ++i)
#pragma unroll
        for (int j = 0; j < 4; ++j)
            acc[i][j] = (floatx4){0.f, 0.f, 0.f, 0.f};

#pragma unroll 1
    for (int kt = 0; kt < NK / 64; ++kt) {
        int k0 = kt * 64;
        __syncthreads();  // previous tile fully consumed
#pragma unroll
        for (int s = 0; s < 4; ++s) {
            int g  = wid * 4 + s;      // 16 groups of 8 rows
            int ml = g * 8 + rloc;
            load_lds16(A + (size_t)(Rm + ml) * NK + k0 + cg * 8, As + g * 512);
        }
#pragma unroll
        for (int s = 0; s < 4; ++s) {
            int g  = wid * 4 + s;
            int nl = g * 8 + rloc;
            load_lds16(Bt + (size_t)(Rn + nl) * NK + k0 + cg * 8, Bs + g * 512);
        }
        __syncthreads();  // compiler drains vmcnt(0) before barrier
#pragma unroll
        for (int ks = 0; ks < 2; ++ks) {
            int ch = (ks * 4 + quad) ^ fx;
            bf16x8 af[4], bfr[4];
#pragma unroll
            for (int mi = 0; mi < 4; ++mi) {
                int ml = wm * 64 + mi * 16 + frow;
                af[mi] = *(const bf16x8*)(As + ml * 64 + ch * 8);
            }
#pragma unroll
            for (int ni = 0; ni < 4; ++ni) {
                int nl = wn * 64 + ni * 16 + frow;
                bfr[ni] = *(const bf16x8*)(Bs + nl * 64 + ch * 8);
            }
#pragma unroll
            for (int mi = 0; mi < 4; ++mi)
#pragma unroll
                for (int ni = 0; ni < 4; ++ni)
                    acc[mi][ni] = __builtin_amdgcn_mfma_f32_16x16x32_bf16(
                        af[mi], bfr[ni], acc[mi][ni], 0, 0, 0);
        }
    }
    // epilogue 1: store C. C/D layout col=lane&15, row=quad*4+reg
#pragma unroll
    for (int mi = 0; mi < 4; ++mi)
#pragma unroll
        for (int ni = 0; ni < 4; ++ni)
#pragma unroll
            for (int r = 0; r < 4; ++r) {
                int row = Rm + wm * 64 + mi * 16 + quad * 4 + r;
                int col = Rn + wn * 64 + ni * 16 + frow;
                C[(size_t)row * NN + col] = f2bf(acc[mi][ni][r]);
            }

    // epilogue 2: fused scan1 — per-(chunk,h) aggregates from the L2-hot tile
    __threadfence();     // drain stores to L2, invalidate L1
    __syncthreads();     // all waves' stores done before any re-read
    int chk = tid >> 6;  // 0..3  (4 chunks of 32 rows in this M-tile)
    int hh  = tid & 63;  // 0..63 (channel within this N-tile)
    const unsigned short* cb = C + (size_t)(Rm + chk * 32) * NN + Rn + 2 * hh;
    float Aagg = 1.f, Vagg = 0.f;
#pragma unroll 1
    for (int tb = 0; tb < CTS; tb += 8) {
        ushort2 kp[8];
#pragma unroll
        for (int j = 0; j < 8; ++j)
            kp[j] = *(const ushort2*)(cb + (size_t)(tb + j) * NN);
#pragma unroll
        for (int j = 0; j < 8; ++j) {
            float a, v;
            gate_av(kp[j].x, kp[j].y, a, v);
            Vagg = a * Vagg + v;
            Aagg *= a;
        }
    }
    int b   = mt >> 5;                 // batch
    int cg2 = (mt & 31) * 4 + chk;     // global chunk index within batch
    int hg  = nt * 64 + hh;            // global channel
    size_t o = ((size_t)b * NH + hg) * NCH + cg2;
    cA[o] = Aagg;
    cV[o] = Vagg;
}

// ---------------- Kernel 3: scan over chunk aggregates --------------------
// one wave per (b,h) channel; lane handles 2 consecutive chunks (float2).
__global__ __launch_bounds__(256) void scan2_kernel(const float* __restrict__ cA,
                                                    const float* __restrict__ cV,
                                                    float* __restrict__ hinit) {
    int w = blockIdx.x * 4 + (threadIdx.x >> 6);  // 0..4095 = channel
    int lane = threadIdx.x & 63;
    int b = w >> 9, h = w & 511;
    const float2* a2p = (const float2*)(cA + ((size_t)b * NH + h) * NCH);
    const float2* v2p = (const float2*)(cV + ((size_t)b * NH + h) * NCH);
    float2 a2 = a2p[lane];
    float2 v2 = v2p[lane];
    // compose the lane's two chunks (apply chunk 2l, then 2l+1)
    float A = a2.y * a2.x;
    float V = a2.y * v2.x + v2.y;
#pragma unroll
    for (int off = 1; off < 64; off <<= 1) {
        float Ap = __shfl_up(A, off, 64);
        float Vp = __shfl_up(V, off, 64);
        if (lane >= off) { V = A * Vp + V; A = A * Ap; }
    }
    float excl = __shfl_up(V, 1, 64);
    if (lane == 0) excl = 0.f;
    float e0 = excl;               // h entering chunk 2*lane
    float e1 = a2.x * e0 + v2.x;   // h entering chunk 2*lane+1
    hinit[((size_t)b * NCH + 2 * lane) * NH + h]     = e0;
    hinit[((size_t)b * NCH + 2 * lane + 1) * NH + h] = e1;
}

// ---------------- Kernel 4: replay chunks, write out & hidden -------------
// gh is channel-interleaved: one contiguous ushort8 (k,p x4) per thread per t.
__global__ __launch_bounds__(128) void scan3_kernel(const unsigned short* __restrict__ gh,
                                                    const float* __restrict__ hinit,
                                                    const float* __restrict__ x,
                                                    float* __restrict__ out,
                                                    float* __restrict__ hidden) {
    int b = blockIdx.x >> 7, c = blockIdx.x & 127;
    int h = threadIdx.x * 4;
    size_t row0 = (size_t)(b * NT + c * CTS);
    const unsigned short* base = gh + row0 * NN + 2 * h;
    const float* xb = x + row0 * ND + h;
    float* ob = out + row0 * ND + h;
    float4 hv = *(const float4*)(hinit + ((size_t)b * NCH + c) * NH + h);
#pragma unroll 1
    for (int tb = 0; tb < CTS; tb += 8) {
        ushortx8 kp[8];
        float4 xv[8];
#pragma unroll
        for (int j = 0; j < 8; ++j) {
            kp[j] = *(const ushortx8*)(base + (size_t)(tb + j) * NN);
            xv[j] = *(const float4*)(xb + (size_t)(tb + j) * ND);
        }
#pragma unroll
        for (int j = 0; j < 8; ++j) {
            float a, v;
            gate_av(kp[j][0], kp[j][1], a, v); hv.x = a * hv.x + v;
            gate_av(kp[j][2], kp[j][3], a, v); hv.y = a * hv.y + v;
            gate_av(kp[j][4], kp[j][5], a, v); hv.z = a * hv.z + v;
            gate_av(kp[j][6], kp[j][7], a, v); hv.w = a * hv.w + v;
            float4 ov;
            ov.x = hv.x + xv[j].x; ov.y = hv.y + xv[j].y;
            ov.z = hv.z + xv[j].z; ov.w = hv.w + xv[j].w;
            *(float4*)(ob + (size_t)(tb + j) * ND) = ov;
        }
    }
    if (c == NCH - 1)
        *(float4*)(hidden + (size_t)b * NH + h) = hv;
}

extern "C" void kernel_launch(void* const* d_in, const int* in_sizes, int n_in,
                              void* d_out, int out_size, void* d_ws, size_t ws_size,
                              hipStream_t stream) {
    const float* x     = (const float*)d_in[0];
    const float* gamma = (const float*)d_in[1];
    const float* beta  = (const float*)d_in[2];
    const float* W     = (const float*)d_in[3];

    float* out    = (float*)d_out;
    float* hidden = out + (size_t)NM * ND;

    // ws layout: Wt(1MB) | gh(64MB) | cA(2MB) | cV(2MB) | hinit(2MB) = 71MB
    char* ws = (char*)d_ws;
    unsigned short* Wt = (unsigned short*)ws;
    unsigned short* gh = (unsigned short*)(ws + (size_t)(1u << 20));
    float* cA    = (float*)(ws + (size_t)(1u << 20) + (size_t)NM * NN * 2);
    float* cV    = cA + (size_t)NB * NCH * NH;
    float* hinit = cV + (size_t)NB * NCH * NH;
    // xn scratch lives in d_out (dead before scan3 overwrites the region)
    unsigned short* xn = (unsigned short*)d_out;

    prep_kernel<<<512 + NM / 4, 256, 0, stream>>>(x, gamma, beta, W, xn, Wt);
    gemm_kernel<<<2048, 256, 0, stream>>>(xn, Wt, gh, cA, cV);
    scan2_kernel<<<1024, 256, 0, stream>>>(cA, cV, hinit);
    scan3_kernel<<<NB * NCH, 128, 0, stream>>>(gh, hinit, x, out, hidden);
}